// Round 6
// baseline (4915.594 us; speedup 1.0000x reference)
//
#include <hip/hip_runtime.h>

#define T_LEN 2048

typedef _Float16 f16x8 __attribute__((ext_vector_type(8)));
typedef float f32x4 __attribute__((ext_vector_type(4)));
typedef unsigned int u32;

__device__ __forceinline__ float sigm(float v) { return 1.f / (1.f + __expf(-v)); }

// XOR-swizzled address into A tile [16 seq][512 k] f16 (row stride 1024B).
__device__ __forceinline__ void* swzA(_Float16* base, int row, int k) {
  int byte = row * 1024 + k * 2;
  byte ^= (row & 7) << 4;
  return (void*)((char*)base + byte);
}

// Issue 3 L2-coherent (L1-bypass) pollers without waiting.
__device__ __forceinline__ void issue3_sc0(const u32* p1, const u32* p2,
                                           const u32* p3, u32& a, u32& b,
                                           u32& c) {
  asm volatile(
      "global_load_dword %0, %3, off sc0\n\t"
      "global_load_dword %1, %4, off sc0\n\t"
      "global_load_dword %2, %5, off sc0"
      : "=&v"(a), "=&v"(b), "=&v"(c)
      : "v"(p1), "v"(p2), "v"(p3)
      : "memory");
}
__device__ __forceinline__ void wait3(u32& a, u32& b, u32& c) {
  asm volatile("s_waitcnt vmcnt(0)" : "+v"(a), "+v"(b), "+v"(c)::"memory");
}

// Grid: 32 WGs x 1024 threads; active iff (bid&7)<4.
//  role: group g = bid&7 {dir,bh} -> 16 seqs; member m = bid>>3 owns dims [64m..+63].
//  Members of group g sit at bids {g,g+8,g+16,g+24} == g (mod 8) -> same XCD
//  under round-robin dispatch -> polls served by the shared XCD L2 (sc0).
//  Fallback: a thread failing 24 sc0 samples flips permanently to MALL loads.
// Exchange: u32 {stamp16|h-f16} per (seq,dim), double-buffered by t&1.
__global__ __launch_bounds__(1024, 4) void bilstm_kernel(
    const float* __restrict__ x, const float* __restrict__ Wfw,
    const float* __restrict__ bfw, const float* __restrict__ Wbw,
    const float* __restrict__ bbw, float* __restrict__ out,
    u32* __restrict__ hglob) {
  const int bid = blockIdx.x;
  if ((bid & 7) >= 4) return;  // spare WGs (placement padding) exit
  const int g = bid & 7;
  const int m = bid >> 3;
  const int dir = g >> 1, bh = g & 1;
  const int tid = threadIdx.x;
  const int w = tid >> 6;
  const int lane = tid & 63;
  const int l15 = lane & 15, l4 = lane >> 4;

  const float* W = dir ? Wbw : Wfw;
  const float* bias = dir ? bbw : bfw;

  __shared__ _Float16 Alds[16 * 512];  // 16KB swizzled [seq][k<256:x, k>=256:h]
  __shared__ float Glds[16 * 260];     // gates [seq][256 cols], stride 260

  // ---- weight slice: one 16-col tile x K=512 -> 64 VGPRs ----
  const int p = w >> 2;
  const int cbase = p * 64 + (w & 3) * 16;  // col within WG's 256
  const int gcol = p * 256 + 64 * m + (w & 3) * 16 + l15;
  f16x8 wB[16];
#pragma unroll
  for (int kk = 0; kk < 16; ++kk) {
    const int kb = kk * 32 + l4 * 8;
    f16x8 h;
#pragma unroll
    for (int j = 0; j < 8; ++j) h[j] = (_Float16)W[(kb + j) * 1024 + gcol];
    wB[kk] = h;
  }
  const float bcol = bias[gcol] + ((p == 2) ? 1.f : 0.f);  // forget bias folded

  // ---- per-thread cell/stage/poll mapping: (seq cs, dim cd) ----
  const int cs = tid >> 6;  // 0..15
  const int cd = tid & 63;  // 0..63
  float c = 0.f;
  bool use_mall = false;

  u32* Hg = hglob + g * (2 * 16 * 256);
  const int pd1 = 64 * ((m + 1) & 3) + cd;
  const int pd2 = 64 * ((m + 2) & 3) + cd;
  const int pd3 = 64 * ((m + 3) & 3) + cd;
  u32* my0 = Hg + (0 * 16 + cs) * 256 + 64 * m + cd;
  u32* my1 = Hg + (1 * 16 + cs) * 256 + 64 * m + cd;

  // prologue: zero A h-half, prefetch x_0
  {
    uint2 z = {0u, 0u};
    *(uint2*)swzA(Alds, cs, 256 + 4 * cd) = z;
  }
  const int tx0 = dir ? (T_LEN - 1) : 0;
  f32x4 xv = *(const f32x4*)(x + (((bh * 16 + cs) * T_LEN + tx0) << 8) + 4 * cd);

  for (int t = 0; t < T_LEN; ++t) {
    const int tx = dir ? (T_LEN - 1 - t) : t;

    // ---- stage x_t (4 f32 -> 4 f16, one 8B LDS write) ----
    {
      union { _Float16 h[4]; uint2 q; } ux;
#pragma unroll
      for (int j = 0; j < 4; ++j) ux.h[j] = (_Float16)xv[j];
      *(uint2*)swzA(Alds, cs, 4 * cd) = ux.q;
    }
    __syncthreads();  // B1: x staged; own h of t-1 staged (pre-B1 last iter)

    // ---- issue first poll sample (sc0: shared-L2 path), no wait yet ----
    const u32 want = (u32)t;
    u32* Hp = Hg + (((t & 1) ^ 1) * 16 + cs) * 256;
    u32 s1 = 0, s2 = 0, s3 = 0;
    if (t > 0) issue3_sc0(Hp + pd1, Hp + pd2, Hp + pd3, s1, s2, s3);

    // ---- prefetch x_{t+1} ----
    {
      const int tn = (t + 1 < T_LEN) ? t + 1 : t;
      const int txn = dir ? (T_LEN - 1 - tn) : tn;
      xv = *(const f32x4*)(x + (((bh * 16 + cs) * T_LEN + txn) << 8) + 4 * cd);
    }

    // ---- pre-detect MFMAs: x tiles (0..7) + OWN h pair (8+2m, 9+2m) ----
    f32x4 acc = {bcol, bcol, bcol, bcol};
#pragma unroll
    for (int kk = 0; kk < 8; ++kk) {
      f16x8 a = *(const f16x8*)swzA(Alds, l15, kk * 32 + l4 * 8);
      acc = __builtin_amdgcn_mfma_f32_16x16x32_f16(a, wB[kk], acc, 0, 0, 0);
    }
#pragma unroll
    for (int q = 0; q < 4; ++q) {
      if (q == m) {  // uniform branch; compile-time register indices
        f16x8 a0 = *(const f16x8*)swzA(Alds, l15, (8 + 2 * q) * 32 + l4 * 8);
        acc = __builtin_amdgcn_mfma_f32_16x16x32_f16(a0, wB[8 + 2 * q], acc, 0, 0, 0);
        f16x8 a1 = *(const f16x8*)swzA(Alds, l15, (9 + 2 * q) * 32 + l4 * 8);
        acc = __builtin_amdgcn_mfma_f32_16x16x32_f16(a1, wB[9 + 2 * q], acc, 0, 0, 0);
      }
    }

    // ---- detect peers' h (sc0 fast path, MALL fallback), stage to LDS ----
    if (t > 0) {
      wait3(s1, s2, s3);
      int tries = 0;
      while ((s1 >> 16) != want || (s2 >> 16) != want || (s3 >> 16) != want) {
        if (use_mall) {
          s1 = __hip_atomic_load(Hp + pd1, __ATOMIC_RELAXED, __HIP_MEMORY_SCOPE_AGENT);
          s2 = __hip_atomic_load(Hp + pd2, __ATOMIC_RELAXED, __HIP_MEMORY_SCOPE_AGENT);
          s3 = __hip_atomic_load(Hp + pd3, __ATOMIC_RELAXED, __HIP_MEMORY_SCOPE_AGENT);
        } else {
          issue3_sc0(Hp + pd1, Hp + pd2, Hp + pd3, s1, s2, s3);
          wait3(s1, s2, s3);
          if (++tries > 24) use_mall = true;  // cross-XCD: L2 line is stale forever
        }
      }
      *(unsigned short*)swzA(Alds, cs, 256 + pd1) = (unsigned short)(s1 & 0xffffu);
      *(unsigned short*)swzA(Alds, cs, 256 + pd2) = (unsigned short)(s2 & 0xffffu);
      *(unsigned short*)swzA(Alds, cs, 256 + pd3) = (unsigned short)(s3 & 0xffffu);
    }
    __syncthreads();  // B2: peer h staged

    // ---- post-detect MFMAs: the 3 peer h pairs ----
#pragma unroll
    for (int q = 0; q < 4; ++q) {
      if (q != m) {
        f16x8 a0 = *(const f16x8*)swzA(Alds, l15, (8 + 2 * q) * 32 + l4 * 8);
        acc = __builtin_amdgcn_mfma_f32_16x16x32_f16(a0, wB[8 + 2 * q], acc, 0, 0, 0);
        f16x8 a1 = *(const f16x8*)swzA(Alds, l15, (9 + 2 * q) * 32 + l4 * 8);
        acc = __builtin_amdgcn_mfma_f32_16x16x32_f16(a1, wB[9 + 2 * q], acc, 0, 0, 0);
      }
    }

    // ---- gates -> LDS transpose (C/D: col=l15, row=4*l4+v) ----
    {
      float* gw = Glds + cbase + l15;
      const int r = l4 * 4;
#pragma unroll
      for (int v = 0; v < 4; ++v) gw[(r + v) * 260] = acc[v];
    }
    __syncthreads();  // B3: gates ready

    // ---- LSTM cell: thread owns (cs, cd) ----
    const float* Gp = Glds + cs * 260 + cd;
    const float gi = Gp[0 * 64], gj = Gp[1 * 64], gf = Gp[2 * 64], go = Gp[3 * 64];
    c = c * sigm(gf) + sigm(gi) * (2.f * sigm(gj + gj) - 1.f);
    const float h = (2.f * sigm(c + c) - 1.f) * sigm(go);

    // publish (agent store -> MALL-visible; also updates/invalidates local L2)
    union { _Float16 hf; unsigned short us; } cv;
    cv.hf = (_Float16)h;
    u32* pub = (t & 1) ? my1 : my0;
    __hip_atomic_store(pub, (((u32)(t + 1)) << 16) | (u32)cv.us,
                       __ATOMIC_RELAXED, __HIP_MEMORY_SCOPE_AGENT);
    // stage own h for next step's pre-detect MFMAs (synced by B1)
    *(unsigned short*)swzA(Alds, cs, 256 + 64 * m + cd) = cv.us;
    __builtin_nontemporal_store(
        h, out + (((bh * 16 + cs) * T_LEN + tx) << 9) + dir * 256 + 64 * m + cd);
  }
}

extern "C" void kernel_launch(void* const* d_in, const int* in_sizes, int n_in,
                              void* d_out, int out_size, void* d_ws,
                              size_t ws_size, hipStream_t stream) {
  const float* x = (const float*)d_in[0];
  const float* Wfw = (const float*)d_in[1];
  const float* bfw = (const float*)d_in[2];
  const float* Wbw = (const float*)d_in[3];
  const float* bbw = (const float*)d_in[4];
  float* out = (float*)d_out;

  // ws: 4 groups x 2 bufs x 16 seq x 256 dims x u32 = 128KB stamped h-lines
  u32* hglob = (u32*)d_ws;
  (void)hipMemsetAsync(hglob, 0, 4 * 2 * 16 * 256 * sizeof(u32), stream);

  bilstm_kernel<<<dim3(32), dim3(1024), 0, stream>>>(x, Wfw, bfw, Wbw, bbw, out,
                                                     hglob);
}